// Round 6
// baseline (251.869 us; speedup 1.0000x reference)
//
#include <hip/hip_runtime.h>
#include <stdint.h>

#define NB 256
#define NL 128
#define ND1 512
#define ND2 512

#define BI 64               // i-tile rows of W per LDS buffer
#define NIT (ND1 / BI)      // 8 i-tiles
#define NKT (ND2 / 32)      // 16 k-tiles of 32 (j-dim)

typedef float float4_t __attribute__((ext_vector_type(4)));
typedef __bf16 bf16x8_t __attribute__((ext_vector_type(8)));
typedef unsigned short ushort8_t __attribute__((ext_vector_type(8)));

// fp32 -> bf16 round-to-nearest-even
__device__ __forceinline__ unsigned short f2bf(float f) {
    unsigned int u = __float_as_uint(f);
    u += 0x7FFFu + ((u >> 16) & 1u);
    return (unsigned short)(u >> 16);
}

__device__ __forceinline__ ushort8_t pack8(float4_t lo, float4_t hi) {
    ushort8_t u;
    u[0] = f2bf(lo.x); u[1] = f2bf(lo.y); u[2] = f2bf(lo.z); u[3] = f2bf(lo.w);
    u[4] = f2bf(hi.x); u[5] = f2bf(hi.y); u[6] = f2bf(hi.z); u[7] = f2bf(hi.w);
    return u;
}

// out[b,l] = sum_ij t1[b,l,i] W[e,i,j] t2[b,l,j]
// Z = T2 x W^T: A = t2 (k=j contiguous) lives ENTIRELY in registers (16 bf16x8 frags);
// W streams through a 2x64KB LDS double buffer, one i-tile (64 x 512) per step.
// One block per batch -> every global byte read once per block. 8 barriers total.
__global__ __launch_bounds__(1024, 4) void pdot_kernel(
    const float* __restrict__ t1, const float* __restrict__ t2,
    const int* __restrict__ pidx, const float* __restrict__ wgt,
    float* __restrict__ out)
{
    __shared__ unsigned short sW[2][BI * ND2];   // 2 x 64 KiB, chunk c of row r stored at c^(r&31)

    const int b  = blockIdx.x;
    const int t  = threadIdx.x;    // 0..1023
    const int wv = t >> 6;         // 0..15
    const int mg = wv >> 1;        // l-group: rows mg*16..+15
    const int ng = wv & 1;         // i-half within tile: cols ng*32..+31
    const int ln = t & 63;
    const int nh = ln & 15;
    const int qd = ln >> 4;

    const int e = pidx[b];
    const float* wp  = wgt + (size_t)e * (ND1 * ND2);
    const float* t1p = t1  + (size_t)b * (NL * ND1);

    // staging map: thread owns row sr (0..63), chunks sc+16q (q=0..3); chunk = 8 floats in / 8 bf16 out
    const int sr  = t >> 4;
    const int sc  = t & 15;
    const int ssw = sr & 31;

    // ---- preload A (t2) fragments: lane holds t2[b, mg*16+nh, kt*32+qd*8 .. +7] for all 16 kt
    const int lrow = mg * 16 + nh;
    const float* aRow = t2 + (size_t)b * (NL * ND2) + (size_t)lrow * ND2 + qd * 8;
    bf16x8_t afrag[NKT];
    #pragma unroll
    for (int kt = 0; kt < NKT; ++kt) {
        float4_t lo = *(const float4_t*)(aRow + kt * 32);
        float4_t hi = *(const float4_t*)(aRow + kt * 32 + 4);
        afrag[kt] = __builtin_bit_cast(bf16x8_t, pack8(lo, hi));
    }

    // ---- stage W i-tile 0 into buf 0
    {
        const float* src = wp + (size_t)sr * ND2;
        unsigned short* dst = &sW[0][sr * ND2];
        #pragma unroll
        for (int q = 0; q < 4; ++q) {
            const int c = sc + 16 * q;
            float4_t lo = *(const float4_t*)(src + c * 8);
            float4_t hi = *(const float4_t*)(src + c * 8 + 4);
            *(ushort8_t*)(dst + (c ^ ssw) * 8) = pack8(lo, hi);
        }
    }
    __syncthreads();

    // B-fragment rows for this wave (within tile): ng*32 + {0,16} + nh
    const int r0 = ng * 32 + nh;
    const int r1 = ng * 32 + 16 + nh;
    const unsigned short* wb0base;  // computed per buffer below
    const int sw0 = r0 & 31;
    const int sw1 = r1 & 31;

    float4_t ps = {0.f, 0.f, 0.f, 0.f};   // running per-lane partial of out rows

    for (int it = 0; it < NIT; ++it) {
        const int cur = it & 1;

        // stage tile it+1 into the other buffer (loads issue first; MFMA below overlaps latency
        // via the 3 other waves on this SIMD)
        if (it < NIT - 1) {
            const float* src = wp + (size_t)((it + 1) * BI + sr) * ND2;
            unsigned short* dst = &sW[cur ^ 1][sr * ND2];
            #pragma unroll
            for (int q = 0; q < 4; ++q) {
                const int c = sc + 16 * q;
                float4_t lo = *(const float4_t*)(src + c * 8);
                float4_t hi = *(const float4_t*)(src + c * 8 + 4);
                *(ushort8_t*)(dst + (c ^ ssw) * 8) = pack8(lo, hi);
            }
        }

        // MFMA phase on buf cur: 16 kt x 2 ns
        float4_t acc0 = {0.f, 0.f, 0.f, 0.f};
        float4_t acc1 = {0.f, 0.f, 0.f, 0.f};
        const unsigned short* sb = &sW[cur][0];
        #pragma unroll
        for (int kt = 0; kt < NKT; ++kt) {
            const int c = kt * 4 + qd;
            bf16x8_t b0 = __builtin_bit_cast(bf16x8_t,
                *(const ushort8_t*)(sb + r0 * ND2 + (c ^ sw0) * 8));
            acc0 = __builtin_amdgcn_mfma_f32_16x16x32_bf16(afrag[kt], b0, acc0, 0, 0, 0);
            bf16x8_t b1 = __builtin_bit_cast(bf16x8_t,
                *(const ushort8_t*)(sb + r1 * ND2 + (c ^ sw1) * 8));
            acc1 = __builtin_amdgcn_mfma_f32_16x16x32_bf16(afrag[kt], b1, acc1, 0, 0, 0);
        }

        // fold epilogue: ps[r] += Z[l, i]*t1[l, i] for this i-tile
        // C/D: col(i-local) = ns*16+nh, row(l) = mg*16 + qd*4 + r
        const int colbase = it * BI + ng * 32;
        #pragma unroll
        for (int r = 0; r < 4; ++r) {
            const int row = mg * 16 + qd * 4 + r;
            ps[r] += acc0[r] * t1p[(size_t)row * ND1 + colbase + nh]
                   + acc1[r] * t1p[(size_t)row * ND1 + colbase + 16 + nh];
        }

        __syncthreads();
    }
    (void)wb0base;

    // ---- final reduce: sum ps[r] across the 16 nh-lanes of each quad, one atomic per (wave,row)
    #pragma unroll
    for (int r = 0; r < 4; ++r) {
        float v = ps[r];
        v += __shfl_xor(v, 1);
        v += __shfl_xor(v, 2);
        v += __shfl_xor(v, 4);
        v += __shfl_xor(v, 8);
        if (nh == 0) atomicAdd(&out[b * NL + mg * 16 + qd * 4 + r], v);
    }
}

extern "C" void kernel_launch(void* const* d_in, const int* in_sizes, int n_in,
                              void* d_out, int out_size, void* d_ws, size_t ws_size,
                              hipStream_t stream)
{
    const float* t1  = (const float*)d_in[0];
    const float* t2  = (const float*)d_in[1];
    const int* pidx  = (const int*)d_in[2];
    const float* wgt = (const float*)d_in[3];
    float* out = (float*)d_out;

    hipMemsetAsync(out, 0, (size_t)out_size * sizeof(float), stream);
    pdot_kernel<<<dim3(NB), dim3(1024), 0, stream>>>(t1, t2, pidx, wgt, out);
}